// Round 11
// baseline (1404.763 us; speedup 1.0000x reference)
//
#include <hip/hip_runtime.h>
#include <hip/hip_fp16.h>

// AGCRN: B=32 T=12 N=1024 C=2 D=16 H=64 K=2 OUT=12
// Cross-layer pipeline (round 10) + XCD-aware gemm block swizzle (round 11):
// all 16 row-tiles of one col-tile map to one XCD (blk%8 assumed XCD id) so the
// B col-tile is fetched into that XCD's L2 once and re-used 16x (was 16 L3 re-reads).
// Bit-exact vs round 9/10.

typedef _Float16 f16x8 __attribute__((ext_vector_type(8)));
typedef _Float16 f16x4 __attribute__((ext_vector_type(4)));
typedef float f32x4 __attribute__((ext_vector_type(4)));

// ---------------- A = softmax(relu(E E^T)) -> fp16 ----------------
__global__ __launch_bounds__(256) void compute_A_kernel(const float* __restrict__ E,
                                                        __half* __restrict__ Ah) {
  int n = blockIdx.x;
  int tid = threadIdx.x;
  __shared__ float red[256];
  float en[16];
#pragma unroll
  for (int d = 0; d < 16; ++d) en[d] = E[n * 16 + d];
  float v[4];
#pragma unroll
  for (int q = 0; q < 4; ++q) {
    int m = tid + q * 256;
    const float* Em = E + m * 16;
    float dot = 0.f;
#pragma unroll
    for (int d = 0; d < 16; ++d) dot += en[d] * Em[d];
    v[q] = fmaxf(dot, 0.f);
  }
  float mx = fmaxf(fmaxf(v[0], v[1]), fmaxf(v[2], v[3]));
  red[tid] = mx; __syncthreads();
  for (int s = 128; s > 0; s >>= 1) { if (tid < s) red[tid] = fmaxf(red[tid], red[tid + s]); __syncthreads(); }
  mx = red[0];
  __syncthreads();
  float e[4], sum = 0.f;
#pragma unroll
  for (int q = 0; q < 4; ++q) { e[q] = expf(v[q] - mx); sum += e[q]; }
  red[tid] = sum; __syncthreads();
  for (int s = 128; s > 0; s >>= 1) { if (tid < s) red[tid] += red[tid + s]; __syncthreads(); }
  float inv = 1.f / red[0];
#pragma unroll
  for (int q = 0; q < 4; ++q) Ah[(size_t)n * 1024 + tid + q * 256] = __float2half(e[q] * inv);
}

// ---------------- E16[n][d] fp16, d padded 16->32 with zeros ----------------
__global__ void build_e16_kernel(const float* __restrict__ E, __half* __restrict__ E16) {
  int t = blockIdx.x * 256 + threadIdx.x;
  if (t >= 1024 * 32) return;
  int d = t & 31;
  E16[t] = (d < 16) ? __float2half(E[(t >> 5) * 16 + d]) : __half(0);
}

// ---------------- poolT16[j][d]: K-contiguous fp16 pool, j = (seg, o, kip) ----------------
__global__ void pool_t16_kernel(const float* __restrict__ gw0, const float* __restrict__ uw0,
                                const float* __restrict__ gw1, const float* __restrict__ uw1,
                                __half* __restrict__ poolT16) {
  int t = blockIdx.x * 256 + threadIdx.x;
  if (t >= 79872 * 32) return;
  int d = t & 31, j = t >> 5;
  if (d >= 16) { poolT16[t] = __half(0); return; }
  const float* pool; int F, Fp, O, loc;
  if (j < 20480)      { pool = gw0; F = 66;  Fp = 80;  O = 128; loc = j; }
  else if (j < 30720) { pool = uw0; F = 66;  Fp = 80;  O = 64;  loc = j - 20480; }
  else if (j < 63488) { pool = gw1; F = 128; Fp = 128; O = 128; loc = j - 30720; }
  else                { pool = uw1; F = 128; Fp = 128; O = 64;  loc = j - 63488; }
  int KIp = 2 * Fp;
  int o = loc / KIp, kip = loc - o * KIp;
  int kk = (kip >= Fp) ? 1 : 0;
  int jj = kip - kk * Fp;
  int i;
  if (F == Fp) i = jj;
  else i = (jj < 64) ? jj + 2 : (jj < 66 ? jj - 64 : -1);
  poolT16[t] = (i >= 0) ? __float2half(pool[(((size_t)d * 2 + kk) * F + i) * O + o]) : __half(0);
}

// ---------------- Wt via MFMA: Wt[n][j] = sum_d E16[n,d] * poolT16[j,d] ----------------
__global__ __launch_bounds__(256) void make_wt_mfma_kernel(
    const __half* __restrict__ E16g, const __half* __restrict__ poolT16g,
    __half* __restrict__ WtG0, __half* __restrict__ WtU0,
    __half* __restrict__ WtG1, __half* __restrict__ WtU1) {
  __shared__ __align__(16) _Float16 Es[64][40];
  __shared__ __align__(16) _Float16 wbuf[64][264];
  const _Float16* E16 = (const _Float16*)E16g;
  const _Float16* pT = (const _Float16*)poolT16g;
  int bx = blockIdx.x;
  __half* Wt; int OK, jbase;
  if (bx < 80)       { Wt = WtG0; OK = 128 * 160; jbase = bx * 256; }
  else if (bx < 120) { Wt = WtU0; OK = 64 * 160;  jbase = (bx - 80) * 256; }
  else if (bx < 248) { Wt = WtG1; OK = 128 * 256; jbase = (bx - 120) * 256; }
  else               { Wt = WtU1; OK = 64 * 256;  jbase = (bx - 248) * 256; }
  int jglob0 = bx * 256;
  int n0 = blockIdx.y * 64;
  {
    int r = threadIdx.x >> 2, ch = (threadIdx.x & 3) * 8;
    *(f16x8*)&Es[r][ch] = *(const f16x8*)(E16 + (size_t)(n0 + r) * 32 + ch);
  }
  __syncthreads();
  int wave = threadIdx.x >> 6, lane = threadIdx.x & 63;
  int fm = lane & 15, fg = lane >> 4;
  f16x8 af[4];
#pragma unroll
  for (int i = 0; i < 4; ++i) af[i] = *(const f16x8*)&Es[i * 16 + fm][fg * 8];
  f32x4 acc[4][4] = {};
#pragma unroll
  for (int j = 0; j < 4; ++j) {
    int jc = jglob0 + wave * 64 + j * 16 + fm;
    f16x8 bf = *(const f16x8*)(pT + (size_t)jc * 32 + fg * 8);
#pragma unroll
    for (int i = 0; i < 4; ++i)
      acc[i][j] = __builtin_amdgcn_mfma_f32_16x16x32_f16(af[i], bf, acc[i][j], 0, 0, 0);
  }
#pragma unroll
  for (int i = 0; i < 4; ++i)
#pragma unroll
    for (int j = 0; j < 4; ++j)
#pragma unroll
      for (int r = 0; r < 4; ++r)
        wbuf[i * 16 + fg * 4 + r][wave * 64 + j * 16 + fm] = (_Float16)acc[i][j][r];
  __syncthreads();
  for (int idx = threadIdx.x; idx < 64 * 32; idx += 256) {
    int nsub = idx >> 5, pos = (idx & 31) * 8;
    *(float4*)(Wt + (size_t)(n0 + nsub) * OK + jbase + pos) = *(float4*)&wbuf[nsub][pos];
  }
}

// ---------------- merged per-node biases ----------------
__global__ void make_b_all_kernel(const float* __restrict__ E,
                                  const float* __restrict__ gb0, const float* __restrict__ ub0,
                                  const float* __restrict__ gb1, const float* __restrict__ ub1,
                                  float* __restrict__ Bg0, float* __restrict__ Bu0,
                                  float* __restrict__ Bg1, float* __restrict__ Bu1) {
  int tid = blockIdx.x * 256 + threadIdx.x;
  if (tid >= 1024 * 384) return;
  int n = tid / 384, c = tid - n * 384;
  const float* pool; float* outp; int O, o;
  if (c < 128)      { pool = gb0; outp = Bg0; O = 128; o = c; }
  else if (c < 192) { pool = ub0; outp = Bu0; O = 64;  o = c - 128; }
  else if (c < 320) { pool = gb1; outp = Bg1; O = 128; o = c - 192; }
  else              { pool = ub1; outp = Bu1; O = 64;  o = c - 320; }
  const float* En = E + n * 16;
  float a = 0.f;
#pragma unroll
  for (int d = 0; d < 16; ++d) a += En[d] * pool[d * O + o];
  outp[n * O + o] = a;
}

__global__ void zero_kernel(float* __restrict__ p, int count) {
  int i = blockIdx.x * 256 + threadIdx.x;
  if (i < count) p[i] = 0.f;
}

// ---------------- x16[n][t*64+b*2+cc] = src[b][t][n][cc], fp16 node-major ----------------
__global__ void build_x16_kernel(const float* __restrict__ src, __half* __restrict__ x16) {
  int bid = blockIdx.x; int t = bid >> 5, b = bid & 31;
  const float* s = src + (size_t)(b * 12 + t) * 2048;
  __half* dst = x16 + t * 64 + b * 2;
  for (int n = threadIdx.x; n < 1024; n += 256) {
    float2 v = *(const float2*)(s + n * 2);
    *(__half2*)(dst + (size_t)n * 768) = __floats2half2_rn(v.x, v.y);
  }
}

// ---------------- gemm_nt: Y[1024 x Nc] = Ah @ X (64x64 tile) — prelude Axt only ----------
__global__ __launch_bounds__(256) void gemm_nt_kernel(
    const __half* __restrict__ Ahg, const __half* __restrict__ X0g,
    const __half* __restrict__ X1g, __half* __restrict__ Yg,
    int Nc, int cstride, int split) {
  __shared__ __align__(16) _Float16 As[64][136];
  __shared__ __align__(16) _Float16 Bs[64][144];
  const _Float16* __restrict__ Ah = (const _Float16*)Ahg;
  _Float16* __restrict__ Y = (_Float16*)Yg;
  int tid = threadIdx.x;
  int row0 = blockIdx.y * 64;
  int col0 = blockIdx.x * 64;
  const _Float16* __restrict__ Xsrc =
      (col0 < split) ? (const _Float16*)X0g : (const _Float16*)X1g;
  int colg = (col0 < split) ? col0 : col0 - split;
  int wave = tid >> 6, lane = tid & 63;
  int wm = wave & 1, wn = wave >> 1;
  int fm = lane & 15, fg = lane >> 4;

  int sr = tid >> 2, sc = (tid & 3) * 32;
  const _Float16* pa = Ah + (size_t)(row0 + sr) * 1024 + sc;
  int kq = tid & 31, cg = tid >> 5;
  int kb = 4 * kq;
  const _Float16* pb = Xsrc + (size_t)kb * cstride + colg + cg * 8;
  int chunk = kq >> 1;
  int kin = (kq & 1) * 4;

  f16x8 ra[4], rb[4];
#pragma unroll
  for (int c = 0; c < 4; ++c) ra[c] = *(const f16x8*)(pa + c * 8);
#pragma unroll
  for (int r = 0; r < 4; ++r) rb[r] = *(const f16x8*)(pb + (size_t)r * cstride);

  f32x4 acc[2][2] = {};
  for (int k0 = 0; k0 < 1024; k0 += 128) {
#pragma unroll
    for (int c = 0; c < 4; ++c) *(f16x8*)&As[sr][sc + c * 8] = ra[c];
#pragma unroll
    for (int i = 0; i < 8; ++i) {
      int c = cg * 8 + i;
      f16x4 p;
      p[0] = rb[0][i]; p[1] = rb[1][i]; p[2] = rb[2][i]; p[3] = rb[3][i];
      *(f16x4*)&Bs[c][((chunk ^ (c & 7)) << 3) + kin] = p;
    }
    __syncthreads();
    if (k0 + 128 < 1024) {
#pragma unroll
      for (int c = 0; c < 4; ++c) ra[c] = *(const f16x8*)(pa + k0 + 128 + c * 8);
#pragma unroll
      for (int r = 0; r < 4; ++r)
        rb[r] = *(const f16x8*)(pb + (size_t)(k0 + 128 + r) * cstride);
    }
#pragma unroll
    for (int kc = 0; kc < 4; ++kc) {
      int ck = kc * 4 + fg;
      f16x8 af[2], bf[2];
#pragma unroll
      for (int i = 0; i < 2; ++i)
        af[i] = *(const f16x8*)&As[wm * 32 + i * 16 + fm][kc * 32 + fg * 8];
#pragma unroll
      for (int j = 0; j < 2; ++j) {
        int cl = wn * 32 + j * 16 + fm;
        bf[j] = *(const f16x8*)&Bs[cl][(ck ^ (cl & 7)) << 3];
      }
#pragma unroll
      for (int i = 0; i < 2; ++i)
#pragma unroll
        for (int j = 0; j < 2; ++j)
          acc[i][j] = __builtin_amdgcn_mfma_f32_16x16x32_f16(af[i], bf[j], acc[i][j], 0, 0, 0);
    }
    __syncthreads();
  }
#pragma unroll
  for (int i = 0; i < 2; ++i) {
#pragma unroll
    for (int j = 0; j < 2; ++j) {
      int col = col0 + wn * 32 + j * 16 + fm;
      int rbase = row0 + wm * 32 + i * 16 + fg * 4;
#pragma unroll
      for (int r = 0; r < 4; ++r)
        Y[(size_t)(rbase + r) * Nc + col] = (_Float16)acc[i][j][r];
    }
  }
}

// ---------------- gemm_nt128: Y = Ah @ X, 64(M) x 128(N) tile, XCD-swizzled 1D grid ----------
// grid = 16*C blocks (C col-tiles, C multiple of 8 or 16). blk%8 = intended XCD;
// all 16 row-tiles of a col-tile share one XCD -> B col-tile is L2-resident there.
__global__ __launch_bounds__(256) void gemm_nt128_kernel(
    const __half* __restrict__ Ahg, const __half* __restrict__ X0g,
    const __half* __restrict__ X1g, __half* __restrict__ Yg,
    int Nc, int cstride, int split) {
  __shared__ __align__(16) _Float16 As[64][136];
  __shared__ __align__(16) _Float16 Bs[128][144];
  const _Float16* __restrict__ Ah = (const _Float16*)Ahg;
  _Float16* __restrict__ Y = (_Float16*)Yg;
  int tid = threadIdx.x;
  // XCD-aware remap: xcd = blk&7 constant per col-tile group
  int blk = blockIdx.x;
  int xcd = blk & 7;
  int q = blk >> 3;
  int rowT = q & 15;
  int cgrp = q >> 4;
  int row0 = rowT * 64;
  int col0 = (cgrp * 8 + xcd) * 128;
  const _Float16* __restrict__ Xsrc =
      (col0 < split) ? (const _Float16*)X0g : (const _Float16*)X1g;
  int colg = (col0 < split) ? col0 : col0 - split;
  int wave = tid >> 6, lane = tid & 63;
  int fm = lane & 15, fg = lane >> 4;

  int sr = tid >> 2, sc = (tid & 3) * 32;
  const _Float16* pa = Ah + (size_t)(row0 + sr) * 1024 + sc;
  int kq = tid & 31, cg = tid >> 5;
  int kb = 4 * kq;
  const _Float16* pb = Xsrc + (size_t)kb * cstride + colg + cg * 16;
  int chunk = kq >> 1;
  int kin = (kq & 1) * 4;

  f16x8 ra[4], rb[4][2];
#pragma unroll
  for (int c = 0; c < 4; ++c) ra[c] = *(const f16x8*)(pa + c * 8);
#pragma unroll
  for (int r = 0; r < 4; ++r)
#pragma unroll
    for (int h = 0; h < 2; ++h)
      rb[r][h] = *(const f16x8*)(pb + (size_t)r * cstride + h * 8);

  f32x4 acc[4][2] = {};
  for (int k0 = 0; k0 < 1024; k0 += 128) {
#pragma unroll
    for (int c = 0; c < 4; ++c) *(f16x8*)&As[sr][sc + c * 8] = ra[c];
#pragma unroll
    for (int h = 0; h < 2; ++h)
#pragma unroll
      for (int i = 0; i < 8; ++i) {
        int c = cg * 16 + h * 8 + i;
        f16x4 p;
        p[0] = rb[0][h][i]; p[1] = rb[1][h][i]; p[2] = rb[2][h][i]; p[3] = rb[3][h][i];
        *(f16x4*)&Bs[c][((chunk ^ (c & 7)) << 3) + kin] = p;
      }
    __syncthreads();
    if (k0 + 128 < 1024) {
#pragma unroll
      for (int c = 0; c < 4; ++c) ra[c] = *(const f16x8*)(pa + k0 + 128 + c * 8);
#pragma unroll
      for (int r = 0; r < 4; ++r)
#pragma unroll
        for (int h = 0; h < 2; ++h)
          rb[r][h] = *(const f16x8*)(pb + (size_t)(k0 + 128 + r) * cstride + h * 8);
    }
#pragma unroll
    for (int kc = 0; kc < 4; ++kc) {
      int ck = kc * 4 + fg;
      f16x8 af[4], bf[2];
#pragma unroll
      for (int i = 0; i < 4; ++i)
        af[i] = *(const f16x8*)&As[i * 16 + fm][kc * 32 + fg * 8];
#pragma unroll
      for (int j = 0; j < 2; ++j) {
        int cl = wave * 32 + j * 16 + fm;
        bf[j] = *(const f16x8*)&Bs[cl][(ck ^ (cl & 7)) << 3];
      }
#pragma unroll
      for (int i = 0; i < 4; ++i)
#pragma unroll
        for (int j = 0; j < 2; ++j)
          acc[i][j] = __builtin_amdgcn_mfma_f32_16x16x32_f16(af[i], bf[j], acc[i][j], 0, 0, 0);
    }
    __syncthreads();
  }
#pragma unroll
  for (int i = 0; i < 4; ++i) {
#pragma unroll
    for (int j = 0; j < 2; ++j) {
      int col = col0 + wave * 32 + j * 16 + fm;
      int rbase = row0 + i * 16 + fg * 4;
#pragma unroll
      for (int r = 0; r < 4; ++r)
        Y[(size_t)(rbase + r) * Nc + col] = (_Float16)acc[i][j][r];
    }
  }
}

// ---------------- gate0 body: zr=sigmoid([h1|x|Ah1|Ax]@WtG0+Bg0); zh0=z*h1; r0 ----------------
__device__ __forceinline__ void gate0_body(
    _Float16* Xs, int n, int t,
    const __half* __restrict__ h16, const __half* __restrict__ YBD,
    const float* __restrict__ src, const __half* __restrict__ Axt, int tstep,
    const __half* __restrict__ Wtg, const float* __restrict__ Bg,
    const float* __restrict__ h32, __half* __restrict__ zh0, float* __restrict__ r0) {
  constexpr int KIP = 160, STRIDE = 168;
#pragma unroll
  for (int u = 0; u < 2; ++u) {
    int idx = t + u * 256;
    int b = idx >> 4, part = (idx >> 3) & 1, ch = idx & 7;
    const _Float16* s = part ? (const _Float16*)YBD + (size_t)n * 4096 + b * 64 + ch * 8
                             : (const _Float16*)h16 + (size_t)n * 2048 + b * 64 + ch * 8;
    *(f16x8*)&Xs[b * STRIDE + part * 80 + ch * 8] = *(const f16x8*)s;
  }
  if (t < 32) {
    int b = t;
    float2 xv = *(const float2*)(src + ((size_t)(b * 12 + tstep) * 1024 + n) * 2);
    Xs[b * STRIDE + 64] = (_Float16)xv.x;
    Xs[b * STRIDE + 65] = (_Float16)xv.y;
    const _Float16* ax = (const _Float16*)Axt + (size_t)n * 768 + tstep * 64 + b * 2;
    Xs[b * STRIDE + 144] = ax[0];
    Xs[b * STRIDE + 145] = ax[1];
  }
  for (int idx = t; idx < 896; idx += 256) {
    int b = idx / 28, jj = idx % 28;
    int col = (jj < 14) ? 66 + jj : 132 + jj;
    Xs[b * STRIDE + col] = (_Float16)0.f;
  }
  __syncthreads();
  int wave = t >> 6, lane = t & 63;
  int fm = lane & 15, fg = lane >> 4;
  f32x4 acc[2][2] = {};
  const _Float16* Wn = (const _Float16*)Wtg + ((size_t)n * 128 + wave * 32) * KIP;
#pragma unroll
  for (int kc = 0; kc < KIP / 32; ++kc) {
    f16x8 af[2], bf[2];
#pragma unroll
    for (int i = 0; i < 2; ++i)
      af[i] = *(const f16x8*)&Xs[(i * 16 + fm) * STRIDE + kc * 32 + fg * 8];
#pragma unroll
    for (int j = 0; j < 2; ++j)
      bf[j] = *(const f16x8*)(Wn + (size_t)(j * 16 + fm) * KIP + kc * 32 + fg * 8);
#pragma unroll
    for (int i = 0; i < 2; ++i)
#pragma unroll
      for (int j = 0; j < 2; ++j)
        acc[i][j] = __builtin_amdgcn_mfma_f32_16x16x32_f16(af[i], bf[j], acc[i][j], 0, 0, 0);
  }
  const float* Bn = Bg + n * 128;
#pragma unroll
  for (int j = 0; j < 2; ++j) {
    int o = wave * 32 + j * 16 + fm;
    float bias = Bn[o];
#pragma unroll
    for (int i = 0; i < 2; ++i)
#pragma unroll
      for (int r = 0; r < 4; ++r) {
        int b = i * 16 + fg * 4 + r;
        float s = 1.f / (1.f + __expf(-(acc[i][j][r] + bias)));
        size_t base = (size_t)n * 2048 + b * 64;
        if (o < 64) zh0[base + o] = __float2half(s * h32[base + o]);
        else        r0[base + o - 64] = s;
      }
  }
}

// ---------------- upd0 body: hc=tanh([zh0|x|Azh0|Ax]@WtU0+Bu0); h1 = r0*h1+(1-r0)*hc --------
__device__ __forceinline__ void upd0_body(
    _Float16* Xs, int n, int t,
    const __half* __restrict__ zh0, const __half* __restrict__ YCE,
    const float* __restrict__ src, const __half* __restrict__ Axt, int tstep,
    const __half* __restrict__ Wtg, const float* __restrict__ Bu,
    const float* __restrict__ r0, float* __restrict__ h32, __half* __restrict__ h16) {
  constexpr int KIP = 160, STRIDE = 168;
#pragma unroll
  for (int u = 0; u < 2; ++u) {
    int idx = t + u * 256;
    int b = idx >> 4, part = (idx >> 3) & 1, ch = idx & 7;
    const _Float16* s = part ? (const _Float16*)YCE + (size_t)n * 4096 + 2048 + b * 64 + ch * 8
                             : (const _Float16*)zh0 + (size_t)n * 2048 + b * 64 + ch * 8;
    *(f16x8*)&Xs[b * STRIDE + part * 80 + ch * 8] = *(const f16x8*)s;
  }
  if (t < 32) {
    int b = t;
    float2 xv = *(const float2*)(src + ((size_t)(b * 12 + tstep) * 1024 + n) * 2);
    Xs[b * STRIDE + 64] = (_Float16)xv.x;
    Xs[b * STRIDE + 65] = (_Float16)xv.y;
    const _Float16* ax = (const _Float16*)Axt + (size_t)n * 768 + tstep * 64 + b * 2;
    Xs[b * STRIDE + 144] = ax[0];
    Xs[b * STRIDE + 145] = ax[1];
  }
  for (int idx = t; idx < 896; idx += 256) {
    int b = idx / 28, jj = idx % 28;
    int col = (jj < 14) ? 66 + jj : 132 + jj;
    Xs[b * STRIDE + col] = (_Float16)0.f;
  }
  __syncthreads();
  int wave = t >> 6, lane = t & 63;
  int fm = lane & 15, fg = lane >> 4;
  f32x4 acc[2] = {};
  const _Float16* Wn = (const _Float16*)Wtg + ((size_t)n * 64 + wave * 16) * KIP;
#pragma unroll
  for (int kc = 0; kc < KIP / 32; ++kc) {
    f16x8 bf = *(const f16x8*)(Wn + (size_t)fm * KIP + kc * 32 + fg * 8);
#pragma unroll
    for (int i = 0; i < 2; ++i) {
      f16x8 af = *(const f16x8*)&Xs[(i * 16 + fm) * STRIDE + kc * 32 + fg * 8];
      acc[i] = __builtin_amdgcn_mfma_f32_16x16x32_f16(af, bf, acc[i], 0, 0, 0);
    }
  }
  int o = wave * 16 + fm;
  float bias = Bu[n * 64 + o];
#pragma unroll
  for (int i = 0; i < 2; ++i)
#pragma unroll
    for (int r = 0; r < 4; ++r) {
      int b = i * 16 + fg * 4 + r;
      float x = acc[i][r] + bias;
      x = fminf(fmaxf(x, -15.f), 15.f);
      float e = __expf(2.f * x);
      float hc = (e - 1.f) / (e + 1.f);
      size_t base = (size_t)n * 2048 + b * 64;
      float rr = r0[base + o];
      float hnew = rr * h32[base + o] + (1.f - rr) * hc;
      h32[base + o] = hnew;
      h16[base + o] = __float2half(hnew);
    }
}

// ---------------- standalone gate0 / upd0 (prologue) ----------------
__global__ __launch_bounds__(256) void gate0_kernel(
    const __half* __restrict__ h16, const __half* __restrict__ YBD,
    const float* __restrict__ src, const __half* __restrict__ Axt, int tstep,
    const __half* __restrict__ Wtg, const float* __restrict__ Bg,
    const float* __restrict__ h32, __half* __restrict__ zh0, float* __restrict__ r0) {
  __shared__ __align__(16) _Float16 Xs[32 * 168];
  gate0_body(Xs, blockIdx.x, threadIdx.x, h16, YBD, src, Axt, tstep, Wtg, Bg, h32, zh0, r0);
}

__global__ __launch_bounds__(256) void upd0_kernel(
    const __half* __restrict__ zh0, const __half* __restrict__ YCE,
    const float* __restrict__ src, const __half* __restrict__ Axt, int tstep,
    const __half* __restrict__ Wtg, const float* __restrict__ Bu,
    const float* __restrict__ r0, float* __restrict__ h32, __half* __restrict__ h16) {
  __shared__ __align__(16) _Float16 Xs[32 * 168];
  upd0_body(Xs, blockIdx.x, threadIdx.x, zh0, YCE, src, Axt, tstep, Wtg, Bu, r0, h32, h16);
}

// ---------------- F1: gate1(t) + gate0(t+1) ----------------
__global__ __launch_bounds__(256) void gate1_gate0_kernel(
    const __half* __restrict__ h1_16, const __half* __restrict__ h2_16,
    const __half* __restrict__ YBD,
    const __half* __restrict__ WtG1, const float* __restrict__ Bg1,
    const float* __restrict__ h2_32, __half* __restrict__ zh1, float* __restrict__ r1,
    const float* __restrict__ src, const __half* __restrict__ Axt, int tnext,
    const __half* __restrict__ WtG0, const float* __restrict__ Bg0,
    const float* __restrict__ h1_32, __half* __restrict__ zh0, float* __restrict__ r0,
    int do_gate0) {
  constexpr int KIP = 256, STRIDE = 264;
  __shared__ __align__(16) _Float16 Xs[32 * STRIDE];
  int n = blockIdx.x;
  int t = threadIdx.x;
#pragma unroll
  for (int u = 0; u < 4; ++u) {
    int idx = t + u * 256;
    int b = idx >> 5, q = idx & 31;
    const _Float16* s;
    if (q < 8)       s = (const _Float16*)h1_16 + (size_t)n * 2048 + b * 64 + q * 8;
    else if (q < 16) s = (const _Float16*)h2_16 + (size_t)n * 2048 + b * 64 + (q - 8) * 8;
    else if (q < 24) s = (const _Float16*)YBD + (size_t)n * 4096 + b * 64 + (q - 16) * 8;
    else             s = (const _Float16*)YBD + (size_t)n * 4096 + 2048 + b * 64 + (q - 24) * 8;
    *(f16x8*)&Xs[b * STRIDE + q * 8] = *(const f16x8*)s;
  }
  __syncthreads();
  int wave = t >> 6, lane = t & 63;
  int fm = lane & 15, fg = lane >> 4;
  {
    f32x4 acc[2][2] = {};
    const _Float16* Wn = (const _Float16*)WtG1 + ((size_t)n * 128 + wave * 32) * KIP;
#pragma unroll
    for (int kc = 0; kc < KIP / 32; ++kc) {
      f16x8 af[2], bf[2];
#pragma unroll
      for (int i = 0; i < 2; ++i)
        af[i] = *(const f16x8*)&Xs[(i * 16 + fm) * STRIDE + kc * 32 + fg * 8];
#pragma unroll
      for (int j = 0; j < 2; ++j)
        bf[j] = *(const f16x8*)(Wn + (size_t)(j * 16 + fm) * KIP + kc * 32 + fg * 8);
#pragma unroll
      for (int i = 0; i < 2; ++i)
#pragma unroll
        for (int j = 0; j < 2; ++j)
          acc[i][j] = __builtin_amdgcn_mfma_f32_16x16x32_f16(af[i], bf[j], acc[i][j], 0, 0, 0);
    }
    const float* Bn = Bg1 + n * 128;
#pragma unroll
    for (int j = 0; j < 2; ++j) {
      int o = wave * 32 + j * 16 + fm;
      float bias = Bn[o];
#pragma unroll
      for (int i = 0; i < 2; ++i)
#pragma unroll
        for (int r = 0; r < 4; ++r) {
          int b = i * 16 + fg * 4 + r;
          float s = 1.f / (1.f + __expf(-(acc[i][j][r] + bias)));
          size_t base = (size_t)n * 2048 + b * 64;
          if (o < 64) zh1[base + o] = __float2half(s * h2_32[base + o]);
          else        r1[base + o - 64] = s;
        }
    }
  }
  if (!do_gate0) return;
  __syncthreads();
  gate0_body(Xs, n, t, h1_16, YBD, src, Axt, tnext, WtG0, Bg0, h1_32, zh0, r0);
}

// ---------------- F2: upd1(t) + upd0(t+1) ----------------
__global__ __launch_bounds__(256) void upd1_upd0_kernel(
    const __half* __restrict__ h1_16, const __half* __restrict__ zh1,
    const __half* __restrict__ YBD, const __half* __restrict__ YCE,
    const __half* __restrict__ WtU1, const float* __restrict__ Bu1,
    const float* __restrict__ r1, float* __restrict__ h2_32, __half* __restrict__ h2_16,
    const __half* __restrict__ zh0,
    const float* __restrict__ src, const __half* __restrict__ Axt, int tnext,
    const __half* __restrict__ WtU0, const float* __restrict__ Bu0,
    const float* __restrict__ r0, float* __restrict__ h1_32, __half* __restrict__ h1_16w,
    int do_upd0) {
  constexpr int KIP = 256, STRIDE = 264;
  __shared__ __align__(16) _Float16 Xs[32 * STRIDE];
  int n = blockIdx.x;
  int t = threadIdx.x;
#pragma unroll
  for (int u = 0; u < 4; ++u) {
    int idx = t + u * 256;
    int b = idx >> 5, q = idx & 31;
    const _Float16* s;
    if (q < 8)       s = (const _Float16*)h1_16 + (size_t)n * 2048 + b * 64 + q * 8;
    else if (q < 16) s = (const _Float16*)zh1 + (size_t)n * 2048 + b * 64 + (q - 8) * 8;
    else if (q < 24) s = (const _Float16*)YBD + (size_t)n * 4096 + b * 64 + (q - 16) * 8;
    else             s = (const _Float16*)YCE + (size_t)n * 4096 + b * 64 + (q - 24) * 8;
    *(f16x8*)&Xs[b * STRIDE + q * 8] = *(const f16x8*)s;
  }
  __syncthreads();
  int wave = t >> 6, lane = t & 63;
  int fm = lane & 15, fg = lane >> 4;
  {
    f32x4 acc[2] = {};
    const _Float16* Wn = (const _Float16*)WtU1 + ((size_t)n * 64 + wave * 16) * KIP;
#pragma unroll
    for (int kc = 0; kc < KIP / 32; ++kc) {
      f16x8 bf = *(const f16x8*)(Wn + (size_t)fm * KIP + kc * 32 + fg * 8);
#pragma unroll
      for (int i = 0; i < 2; ++i) {
        f16x8 af = *(const f16x8*)&Xs[(i * 16 + fm) * STRIDE + kc * 32 + fg * 8];
        acc[i] = __builtin_amdgcn_mfma_f32_16x16x32_f16(af, bf, acc[i], 0, 0, 0);
      }
    }
    int o = wave * 16 + fm;
    float bias = Bu1[n * 64 + o];
#pragma unroll
    for (int i = 0; i < 2; ++i)
#pragma unroll
      for (int r = 0; r < 4; ++r) {
        int b = i * 16 + fg * 4 + r;
        float x = acc[i][r] + bias;
        x = fminf(fmaxf(x, -15.f), 15.f);
        float e = __expf(2.f * x);
        float hc = (e - 1.f) / (e + 1.f);
        size_t base = (size_t)n * 2048 + b * 64;
        float rr = r1[base + o];
        float hnew = rr * h2_32[base + o] + (1.f - rr) * hc;
        h2_32[base + o] = hnew;
        h2_16[base + o] = __float2half(hnew);
      }
  }
  if (!do_upd0) return;
  __syncthreads();
  upd0_body(Xs, n, t, zh0, YCE, src, Axt, tnext, WtU0, Bu0, r0, h1_32, h1_16w);
}

// ---------------- out[b,o,n] = h2[n,b,:] . conv_w[o,:] + conv_b[o] ----------------
__global__ void final_conv_kernel(const float* __restrict__ h2, const float* __restrict__ cw,
                                  const float* __restrict__ cb, float* __restrict__ out) {
  int tid = blockIdx.x * 256 + threadIdx.x;
  if (tid >= 32 * 1024) return;
  int n = tid & 1023, b = tid >> 10;
  const float* hp = h2 + ((size_t)n * 32 + b) * 64;
  float hv[64];
#pragma unroll
  for (int i = 0; i < 64; ++i) hv[i] = hp[i];
#pragma unroll
  for (int o = 0; o < 12; ++o) {
    float acc = cb[o];
#pragma unroll
    for (int i = 0; i < 64; ++i) acc += hv[i] * cw[o * 64 + i];
    out[((size_t)b * 12 + o) * 1024 + n] = acc;
  }
}

extern "C" void kernel_launch(void* const* d_in, const int* in_sizes, int n_in,
                              void* d_out, int out_size, void* d_ws, size_t ws_size,
                              hipStream_t stream) {
  const float* src = (const float*)d_in[0];
  const float* E   = (const float*)d_in[1];
  const float* gw0 = (const float*)d_in[2];
  const float* gb0 = (const float*)d_in[3];
  const float* uw0 = (const float*)d_in[4];
  const float* ub0 = (const float*)d_in[5];
  const float* gw1 = (const float*)d_in[6];
  const float* gb1 = (const float*)d_in[7];
  const float* uw1 = (const float*)d_in[8];
  const float* ub1 = (const float*)d_in[9];
  const float* cw  = (const float*)d_in[10];
  const float* cb  = (const float*)d_in[11];
  float* out = (float*)d_out;
  (void)in_sizes; (void)n_in; (void)out_size; (void)ws_size;

  char* base = (char*)d_ws;
  size_t off = 0;
  auto alloc = [&](size_t bytes) -> void* {
    void* p = base + off; off += (bytes + 511) & ~(size_t)511; return p;
  };
  __half* Ah   = (__half*)alloc((size_t)1024 * 1024 * 2);           //   2.1 MB
  __half* WtG0 = (__half*)alloc((size_t)1024 * 128 * 160 * 2);      //  41.9 MB
  __half* WtU0 = (__half*)alloc((size_t)1024 * 64 * 160 * 2);       //  21.0 MB
  __half* WtG1 = (__half*)alloc((size_t)1024 * 128 * 256 * 2);      //  67.1 MB
  __half* WtU1 = (__half*)alloc((size_t)1024 * 64 * 256 * 2);       //  33.6 MB
  float*  Bg0  = (float*) alloc((size_t)1024 * 128 * 4);
  float*  Bu0  = (float*) alloc((size_t)1024 * 64 * 4);
  float*  Bg1  = (float*) alloc((size_t)1024 * 128 * 4);
  float*  Bu1  = (float*) alloc((size_t)1024 * 64 * 4);
  // zero-init region (contiguous): h1_32, h2_32, h1_16, h2_16, YBD  (8388608 floats)
  float*  h1_32 = (float*)alloc((size_t)1024 * 2048 * 4);           //   8.4 MB
  float*  h2_32 = (float*)alloc((size_t)1024 * 2048 * 4);           //   8.4 MB
  __half* h1_16 = (__half*)alloc((size_t)1024 * 2048 * 2);          //   4.2 MB
  __half* h2_16 = (__half*)alloc((size_t)1024 * 2048 * 2);          //   4.2 MB
  __half* YBD  = (__half*)alloc((size_t)1024 * 4096 * 2);           //   8.4 MB [A@h1 | A@h2]
  __half* YCE  = (__half*)alloc((size_t)1024 * 4096 * 2);           //   8.4 MB [A@zh1 | A@zh0]
  __half* zh0  = (__half*)alloc((size_t)1024 * 2048 * 2);           //   4.2 MB
  __half* zh1  = (__half*)alloc((size_t)1024 * 2048 * 2);           //   4.2 MB
  __half* Axt  = (__half*)alloc((size_t)1024 * 768 * 2);            //   1.5 MB (A@x all t)
  float*  r1   = (float*) alloc((size_t)1024 * 2048 * 4);           //   8.4 MB
  float*  r0   = (float*) alloc((size_t)1024 * 2048 * 4);           //   8.4 MB (+ prelude scratch)
  __half* poolT16 = (__half*)r0;
  __half* E16  = poolT16 + (size_t)79872 * 32;
  __half* x16  = E16 + (size_t)1024 * 32;
  // total ~235 MB

  // ---- prelude (8 dispatches) ----
  compute_A_kernel<<<1024, 256, 0, stream>>>(E, Ah);
  build_e16_kernel<<<(1024 * 32 + 255) / 256, 256, 0, stream>>>(E, E16);
  pool_t16_kernel<<<(79872 * 32 + 255) / 256, 256, 0, stream>>>(gw0, uw0, gw1, uw1, poolT16);
  make_wt_mfma_kernel<<<dim3(312, 16), 256, 0, stream>>>(E16, poolT16, WtG0, WtU0, WtG1, WtU1);
  make_b_all_kernel<<<(1024 * 384 + 255) / 256, 256, 0, stream>>>(E, gb0, ub0, gb1, ub1,
                                                                  Bg0, Bu0, Bg1, Bu1);
  build_x16_kernel<<<384, 256, 0, stream>>>(src, x16);
  gemm_nt_kernel<<<dim3(12, 16), 256, 0, stream>>>(Ah, (__half*)x16, (__half*)x16, Axt,
                                                   768, 768, 768);
  zero_kernel<<<(8388608 + 255) / 256, 256, 0, stream>>>(h1_32, 8388608);

  // ---- prologue: layer-0 step 0 ----
  gate0_kernel<<<1024, 256, 0, stream>>>(h1_16, YBD, src, Axt, 0, WtG0, Bg0, h1_32, zh0, r0);
  gemm_nt128_kernel<<<256, 256, 0, stream>>>(Ah, zh0, zh0, YCE + 2048,
                                             4096, 2048, 2048);       // YE = A@zh0(0), 16 col-tiles
  upd0_kernel<<<1024, 256, 0, stream>>>(zh0, YCE, src, Axt, 0, WtU0, Bu0, r0, h1_32, h1_16);

  // ---- 12 pipelined iterations (4 dispatches each) ----
  for (int t = 0; t < 12; ++t) {
    int more = (t < 11) ? 1 : 0;
    gemm_nt128_kernel<<<512, 256, 0, stream>>>(Ah, h1_16, h2_16, YBD,
                                               4096, 2048, 2048);     // G1 (XCD-swizzled)
    gate1_gate0_kernel<<<1024, 256, 0, stream>>>(h1_16, h2_16, YBD, WtG1, Bg1, h2_32, zh1, r1,
                                                 src, Axt, t + 1, WtG0, Bg0, h1_32, zh0, r0,
                                                 more);               // F1
    gemm_nt128_kernel<<<512, 256, 0, stream>>>(Ah, zh1, zh0, YCE,
                                               4096, 2048, 2048);     // G2 (XCD-swizzled)
    upd1_upd0_kernel<<<1024, 256, 0, stream>>>(h1_16, zh1, YBD, YCE, WtU1, Bu1, r1,
                                               h2_32, h2_16, zh0, src, Axt, t + 1,
                                               WtU0, Bu0, r0, h1_32, h1_16, more);  // F2
  }

  final_conv_kernel<<<(32 * 1024 + 255) / 256, 256, 0, stream>>>(h2_32, cw, cb, out);
}